// Round 5
// baseline (1177.131 us; speedup 1.0000x reference)
//
#include <hip/hip_runtime.h>
#include <stdint.h>

// LastAggregator: out[n] = msg[argmax_{e: index[e]==n} (t[e], e)] or 0 if node empty.
// Tie-break: max t, then largest event position (matches reference's
// segment_max(where(t==seg_max, pos, -1))).

// Monotone float -> uint32 map (order-preserving for all finite floats).
__device__ __forceinline__ uint32_t f2ord(float f) {
    uint32_t b = __float_as_uint(f);
    return (b & 0x80000000u) ? ~b : (b | 0x80000000u);
}

__global__ void init_keys_kernel(unsigned long long* __restrict__ keys, int n) {
    int stride = gridDim.x * blockDim.x;
    for (int i = blockIdx.x * blockDim.x + threadIdx.x; i < n; i += stride)
        keys[i] = 0ULL;
}

// 2 events per thread, vectorized loads.
__global__ void scatter_argmax_kernel(const int* __restrict__ index,
                                      const float* __restrict__ t,
                                      unsigned long long* __restrict__ keys,
                                      int e) {
    int stride = gridDim.x * blockDim.x;
    int half = e >> 1;  // e is even (2,000,000); pairs [0, half)
    for (int p = blockIdx.x * blockDim.x + threadIdx.x; p < half; p += stride) {
        int2   idx2 = *reinterpret_cast<const int2*>(index + 2 * p);
        float2 t2   = *reinterpret_cast<const float2*>(t + 2 * p);
        unsigned int i0 = 2 * p, i1 = 2 * p + 1;
        unsigned long long k0 = ((unsigned long long)f2ord(t2.x) << 32) | i0;
        unsigned long long k1 = ((unsigned long long)f2ord(t2.y) << 32) | i1;
        atomicMax(&keys[idx2.x], k0);
        atomicMax(&keys[idx2.y], k1);
    }
    // tail (if e odd)
    if ((e & 1) && blockIdx.x == 0 && threadIdx.x == 0) {
        int i = e - 1;
        unsigned long long k = ((unsigned long long)f2ord(t[i]) << 32) | (unsigned int)i;
        atomicMax(&keys[index[i]], k);
    }
}

// 32 lanes per output row; each lane moves one float4 (512 B per row total).
__global__ void gather_rows_kernel(const unsigned long long* __restrict__ keys,
                                   const float* __restrict__ msg,
                                   float* __restrict__ out, int n) {
    int tid  = blockIdx.x * blockDim.x + threadIdx.x;
    int row  = tid >> 5;
    int lane = tid & 31;
    if (row >= n) return;
    unsigned long long key = keys[row];
    float4 v = make_float4(0.f, 0.f, 0.f, 0.f);
    if (key != 0ULL) {
        unsigned int pos = (unsigned int)(key & 0xFFFFFFFFULL);
        v = *reinterpret_cast<const float4*>(msg + (size_t)pos * 128 + lane * 4);
    }
    *reinterpret_cast<float4*>(out + (size_t)row * 128 + lane * 4) = v;
}

extern "C" void kernel_launch(void* const* d_in, const int* in_sizes, int n_in,
                              void* d_out, int out_size, void* d_ws, size_t ws_size,
                              hipStream_t stream) {
    const float* msg   = (const float*)d_in[0];
    const int*   index = (const int*)d_in[1];   // int64 in reference -> int32 per harness
    const float* t     = (const float*)d_in[2];
    float*       out   = (float*)d_out;

    const int E = in_sizes[1];          // 2,000,000
    const int D = 128;
    const int N = out_size / D;         // 100,000

    unsigned long long* keys = (unsigned long long*)d_ws;  // N * 8 bytes

    {
        int blocks = (N + 255) / 256;            // ~391 blocks
        init_keys_kernel<<<blocks, 256, 0, stream>>>(keys, N);
    }
    {
        int pairs  = E >> 1;
        int blocks = (pairs + 255) / 256;
        if (blocks > 2048) blocks = 2048;        // grid-stride the rest
        scatter_argmax_kernel<<<blocks, 256, 0, stream>>>(index, t, keys, E);
    }
    {
        long long threads = (long long)N * 32;
        int blocks = (int)((threads + 255) / 256);
        gather_rows_kernel<<<blocks, 256, 0, stream>>>(keys, msg, out, N);
    }
}